// Round 42
// baseline (168.694 us; speedup 1.0000x reference)
//
#include <hip/hip_runtime.h>
#include <stdint.h>
#include <stddef.h>

#define BATCH   4
#define SEQ     2048
#define HDIM    576
#define NHEADS  9
#define NKV     3
#define HD      64
#define GROUPS  3

typedef __bf16 bf16x8 __attribute__((ext_vector_type(8)));
typedef float  f32x4  __attribute__((ext_vector_type(4)));

__device__ __forceinline__ unsigned short f2bf(float f) {
    union { float f; unsigned u; } x; x.f = f;
    unsigned r = (x.u + 0x7FFFu + ((x.u >> 16) & 1u)) >> 16;
    return (unsigned short)r;
}

__device__ __forceinline__ float bf2f(unsigned short us) {
    union { unsigned u; float f; } x; x.u = ((unsigned)us) << 16;
    return x.f;
}

__device__ __forceinline__ f32x4 mfma16(bf16x8 a, bf16x8 b, f32x4 c) {
    return __builtin_amdgcn_mfma_f32_16x16x32_bf16(a, b, c, 0, 0, 0);
}

// ---------------- Kernel 0: RoPE cos/sin tables [SEQ][32] (verified) ----------------
__global__ void rope_table_kernel(float* __restrict__ cos_t, float* __restrict__ sin_t) {
    int idx = blockIdx.x * blockDim.x + threadIdx.x;
    if (idx >= SEQ * 32) return;
    int s = idx >> 5, i = idx & 31;
    float invf = expf(-(float)i * (9.210340371976184f / 32.0f));  // 10000^(-i/32)
    float ang = (float)s * invf;
    cos_t[idx] = cosf(ang);
    sin_t[idx] = sinf(ang);
}

// ---------------- Kernel 1: MFMA QKV projection, register-RoPE, ROW-TILE PAIRED (VERIFIED r36-r41) ----------------
__launch_bounds__(256, 2)
__global__ void qkv_kernel(const float* __restrict__ x,
                           const float* __restrict__ Wq,
                           const float* __restrict__ Wk,
                           const float* __restrict__ Wv,
                           const float* __restrict__ cos_t,
                           const float* __restrict__ sin_t,
                           unsigned short* __restrict__ qo_ws,
                           unsigned short* __restrict__ k_ws,
                           unsigned short* __restrict__ vT_ws) {
    __shared__ __align__(16) unsigned short aT[2][64][40];
    __shared__ __align__(16) unsigned short bT[64][40];

    const int rt0 = blockIdx.x * 2;  // first of two row tiles
    const int ct = blockIdx.y;       // 0..14: 0-8 Q, 9-11 K, 12-14 V
    const int t = threadIdx.x;
    const int w = t >> 6, l = t & 63;
    const int lr = l & 15, lk8 = (l >> 4) * 8;

    const float* W; int wbase;
    if (ct < 9)       { W = Wq; wbase = ct * 64; }
    else if (ct < 12) { W = Wk; wbase = (ct - 9) * 64; }
    else              { W = Wv; wbase = (ct - 12) * 64; }

    const int arow = t >> 2, kg = t & 3;

    f32x4 acc[2][4];
#pragma unroll
    for (int hf = 0; hf < 2; ++hf)
#pragma unroll
        for (int nf = 0; nf < 4; ++nf)
#pragma unroll
            for (int i = 0; i < 4; ++i) acc[hf][nf][i] = 0.0f;

    for (int k0 = 0; k0 < HDIM; k0 += 32) {
        __syncthreads();
        // stage A for BOTH row tiles
#pragma unroll
        for (int hf = 0; hf < 2; ++hf) {
            const float4* ap = reinterpret_cast<const float4*>(
                x + (size_t)((rt0 + hf) * 64 + arow) * HDIM + k0 + kg * 8);
            float4 a0 = ap[0], a1 = ap[1];
            unsigned short* p = &aT[hf][arow][kg * 8];
            p[0] = f2bf(a0.x); p[1] = f2bf(a0.y); p[2] = f2bf(a0.z); p[3] = f2bf(a0.w);
            p[4] = f2bf(a1.x); p[5] = f2bf(a1.y); p[6] = f2bf(a1.z); p[7] = f2bf(a1.w);
        }
        // stage B ONCE (shared by both row tiles)
        {
            const float4* bp = reinterpret_cast<const float4*>(
                W + (size_t)(wbase + arow) * HDIM + k0 + kg * 8);
            float4 b0 = bp[0], b1 = bp[1];
            unsigned short* p = &bT[arow][kg * 8];
            p[0] = f2bf(b0.x); p[1] = f2bf(b0.y); p[2] = f2bf(b0.z); p[3] = f2bf(b0.w);
            p[4] = f2bf(b1.x); p[5] = f2bf(b1.y); p[6] = f2bf(b1.z); p[7] = f2bf(b1.w);
        }
        __syncthreads();

#pragma unroll
        for (int hf = 0; hf < 2; ++hf) {
            bf16x8 af = *reinterpret_cast<const bf16x8*>(&aT[hf][w * 16 + lr][lk8]);
#pragma unroll
            for (int nf = 0; nf < 4; ++nf) {
                bf16x8 bfr = *reinterpret_cast<const bf16x8*>(&bT[nf * 16 + lr][lk8]);
                acc[hf][nf] = mfma16(af, bfr, acc[hf][nf]);
            }
        }
    }

    // ---- epilogue: register RoPE + DIRECT global stores (verified, looped over halves) ----
    const float QSCALE = 0.18033688011112042f;   // 0.125 * log2(e), folded into Q
    const int rowin = w * 16 + (l >> 4) * 4;
#pragma unroll
    for (int hf = 0; hf < 2; ++hf) {
        const int rt = rt0 + hf;
#pragma unroll
        for (int r = 0; r < 4; ++r) {
            const int grow = rt * 64 + rowin + r;
            const int b = grow >> 11, s = grow & 2047;
            if (ct < 12) {
#pragma unroll
                for (int nf = 0; nf < 2; ++nf) {
                    const int d = nf * 16 + lr;                  // 0..31
                    const float c  = cos_t[s * 32 + d];
                    const float sn = sin_t[s * 32 + d];
                    const float lo = acc[hf][nf][r];             // col d
                    const float hi = acc[hf][nf + 2][r];         // col d+32
                    if (ct < 9) {
                        const size_t base = (size_t)grow * HDIM + ct * 64;
                        qo_ws[base + d]      = f2bf((lo * c - hi * sn) * QSCALE);
                        qo_ws[base + d + 32] = f2bf((hi * c + lo * sn) * QSCALE);
                    } else {
                        const size_t base = (((size_t)(b * NKV + (ct - 9))) * SEQ + s) * HD;
                        k_ws[base + d]      = f2bf(lo * c - hi * sn);
                        k_ws[base + d + 32] = f2bf(hi * c + lo * sn);
                    }
                }
            } else {
                // V transposed: vT_ws[(b*NKV+kh)*HD*SEQ + d*SEQ + s]
                const size_t base = ((size_t)(b * NKV + (ct - 12))) * SEQ * HD;
#pragma unroll
                for (int nf = 0; nf < 4; ++nf)
                    vT_ws[base + (size_t)(nf * 16 + lr) * SEQ + s] = f2bf(acc[hf][nf][r]);
            }
        }
    }
}

// ---------------- Kernel 2: MFMA causal flash attention, MERGED-PHASE + INTERLEAVED QK^T ----------------
// r41-verified body; change: when tile A is active, BOTH QK^T MFMA clusters issue before
// A's softmax, so B's MFMAs are in flight during A's softmax dependency stall (MFMA/VALU
// are separate pipes). Single pT stays safe: A's PV reads precede B's pT writes in-order.
__launch_bounds__(256, 2)
__global__ void attn_mfma(unsigned short* __restrict__ qo_ws,
                          const unsigned short* __restrict__ k_ws,
                          const unsigned short* __restrict__ vT_ws) {
    __shared__ __align__(16) unsigned short kT[64][72];
    __shared__ __align__(16) unsigned short vT[64][72];   // [d][kv]
    __shared__ __align__(16) unsigned short pT[4][16][72];

    // ---- XCD-aware work-id swizzle (bijective for 576 blocks, verified r28..r41) ----
    const int flat = blockIdx.x + 16 * (blockIdx.y + 9 * blockIdx.z);  // 0..575 launch id
    const int wsort = (flat % 8) * 72 + (flat / 8);                    // same-XCD => contiguous work
    const int g = wsort / 48;                 // 0..11 = b*3 + kh
    const int rem = wsort % 48;
    const int b = g / 3, kh = g % 3;
    const int hg = rem / 16, pairi = rem % 16;
    const int h = kh * 3 + hg;

    const int t = threadIdx.x, w = t >> 6, l = t & 63;
    const int lr = l & 15, lk8 = (l >> 4) * 8;

    const size_t kvbase = ((size_t)(b * NKV + kh)) * SEQ * HD;  // same extent for k_ws and vT_ws
    const int row = t >> 3, c8 = (t & 7) * 8;
    const int srow_in = w * 16 + (l >> 4) * 4;

    const float THR2 = 11.541560327111708f;    // 8 nats in log2 units

    const int qtA = pairi;          // small tile
    const int qtB = 31 - pairi;     // large tile (qtA < qtB always: pairi <= 15)

    // ---- Q fragments for BOTH tiles (pre-scaled by 0.125*log2e at qkv time) ----
    size_t qbaseA = ((size_t)(b * SEQ + qtA * 64 + w * 16 + lr)) * HDIM + h * 64;
    size_t qbaseB = ((size_t)(b * SEQ + qtB * 64 + w * 16 + lr)) * HDIM + h * 64;
    bf16x8 qaA[2], qaB[2];
    qaA[0] = *reinterpret_cast<const bf16x8*>(&qo_ws[qbaseA + lk8]);
    qaA[1] = *reinterpret_cast<const bf16x8*>(&qo_ws[qbaseA + 32 + lk8]);
    qaB[0] = *reinterpret_cast<const bf16x8*>(&qo_ws[qbaseB + lk8]);
    qaB[1] = *reinterpret_cast<const bf16x8*>(&qo_ws[qbaseB + 32 + lk8]);

    float mA[4], mB[4], sumA[4], sumB[4];
    f32x4 oaccA[4], oaccB[4];
#pragma unroll
    for (int r = 0; r < 4; ++r) { mA[r] = -1e30f; mB[r] = -1e30f; sumA[r] = 0.f; sumB[r] = 0.f; }
#pragma unroll
    for (int nf = 0; nf < 4; ++nf)
#pragma unroll
        for (int i = 0; i < 4; ++i) { oaccA[nf][i] = 0.0f; oaccB[nf][i] = 0.0f; }

    uint4 kreg[2], vreg[2];
    // prologue: load tile 0 into regs, then LDS
#pragma unroll
    for (int it = 0; it < 2; ++it) {
        int rr = it * 32 + row;
        kreg[it] = *reinterpret_cast<const uint4*>(&k_ws[kvbase + (size_t)rr * HD + c8]);
        vreg[it] = *reinterpret_cast<const uint4*>(&vT_ws[kvbase + (size_t)rr * SEQ + c8]);
    }
    __syncthreads();
#pragma unroll
    for (int it = 0; it < 2; ++it) {
        int rr = it * 32 + row;
        *reinterpret_cast<uint4*>(&kT[rr][c8]) = kreg[it];
        *reinterpret_cast<uint4*>(&vT[rr][c8]) = vreg[it];
    }
    __syncthreads();

    for (int kt = 0; kt <= qtB; ++kt) {
        const bool aActive = (kt <= qtA);

        // ---- prefetch next tile into registers (latency hidden under compute) ----
        if (kt < qtB) {
#pragma unroll
            for (int it = 0; it < 2; ++it) {
                int rr = it * 32 + row;
                kreg[it] = *reinterpret_cast<const uint4*>(
                    &k_ws[kvbase + (size_t)((kt + 1) * 64 + rr) * HD + c8]);
                vreg[it] = *reinterpret_cast<const uint4*>(
                    &vT_ws[kvbase + (size_t)rr * SEQ + (kt + 1) * 64 + c8]);
            }
        }

        // ---- BOTH QK^T MFMA clusters issued before any softmax (ILP across tiles) ----
        f32x4 saccA[4], saccB[4];
#pragma unroll
        for (int nf = 0; nf < 4; ++nf)
#pragma unroll
            for (int i = 0; i < 4; ++i) { saccA[nf][i] = 0.0f; saccB[nf][i] = 0.0f; }

        __builtin_amdgcn_s_setprio(1);
        if (aActive) {
#pragma unroll
            for (int kf = 0; kf < 2; ++kf)
#pragma unroll
                for (int nf = 0; nf < 4; ++nf) {
                    bf16x8 bfr = *reinterpret_cast<const bf16x8*>(&kT[nf * 16 + lr][kf * 32 + lk8]);
                    saccA[nf] = mfma16(qaA[kf], bfr, saccA[nf]);
                }
        }
#pragma unroll
        for (int kf = 0; kf < 2; ++kf)
#pragma unroll
            for (int nf = 0; nf < 4; ++nf) {
                bf16x8 bfr = *reinterpret_cast<const bf16x8*>(&kT[nf * 16 + lr][kf * 32 + lk8]);
                saccB[nf] = mfma16(qaB[kf], bfr, saccB[nf]);
            }
        __builtin_amdgcn_s_setprio(0);

        // ================= TILE A softmax + PV (B's MFMAs still in flight) =================
        if (aActive) {
            float sv[4][4], lmax[4];
            if (kt == qtA) {
#pragma unroll
                for (int r = 0; r < 4; ++r) {
                    int qrow = qtA * 64 + srow_in + r;
                    float mx = -1e30f;
#pragma unroll
                    for (int nf = 0; nf < 4; ++nf) {
                        float sc = saccA[nf][r];
                        int kcol = kt * 64 + nf * 16 + lr;
                        if (kcol > qrow) sc = -1e30f;
                        sv[nf][r] = sc;
                        mx = fmaxf(mx, sc);
                    }
                    lmax[r] = mx;
                }
            } else {
#pragma unroll
                for (int r = 0; r < 4; ++r) {
                    float mx = -1e30f;
#pragma unroll
                    for (int nf = 0; nf < 4; ++nf) {
                        float sc = saccA[nf][r];
                        sv[nf][r] = sc;
                        mx = fmaxf(mx, sc);
                    }
                    lmax[r] = mx;
                }
            }

            bool grow = false;
#pragma unroll
            for (int r = 0; r < 4; ++r) grow = grow || (lmax[r] > mA[r] + THR2);
            if (__any(grow)) {
#pragma unroll
                for (int r = 0; r < 4; ++r) {
                    float mx = lmax[r];
#pragma unroll
                    for (int off = 1; off < 16; off <<= 1) mx = fmaxf(mx, __shfl_xor(mx, off, 64));
                    float newm = fmaxf(mA[r], mx);
                    float corr = exp2f(mA[r] - newm);
                    sumA[r] *= corr;
#pragma unroll
                    for (int nf = 0; nf < 4; ++nf) oaccA[nf][r] *= corr;
                    mA[r] = newm;
                }
            }

            float p[4][4];
#pragma unroll
            for (int r = 0; r < 4; ++r) {
#pragma unroll
                for (int nf = 0; nf < 4; ++nf) {
                    float pv = exp2f(sv[nf][r] - mA[r]);
                    p[nf][r] = pv;
                    sumA[r] += pv;
                }
            }

#pragma unroll
            for (int r = 0; r < 4; ++r)
#pragma unroll
                for (int nf = 0; nf < 4; ++nf)
                    pT[w][(l >> 4) * 4 + r][nf * 16 + lr] = f2bf(p[nf][r]);

            __builtin_amdgcn_s_setprio(1);
#pragma unroll
            for (int kf = 0; kf < 2; ++kf) {
                bf16x8 pa = *reinterpret_cast<const bf16x8*>(&pT[w][lr][kf * 32 + lk8]);
#pragma unroll
                for (int nf = 0; nf < 4; ++nf) {
                    bf16x8 vb = *reinterpret_cast<const bf16x8*>(&vT[nf * 16 + lr][kf * 32 + lk8]);
                    oaccA[nf] = mfma16(pa, vb, oaccA[nf]);
                }
            }
            __builtin_amdgcn_s_setprio(0);
        }

        // ================= TILE B softmax + PV =================
        {
            float sv[4][4], lmax[4];
            if (kt == qtB) {
#pragma unroll
                for (int r = 0; r < 4; ++r) {
                    int qrow = qtB * 64 + srow_in + r;
                    float mx = -1e30f;
#pragma unroll
                    for (int nf = 0; nf < 4; ++nf) {
                        float sc = saccB[nf][r];
                        int kcol = kt * 64 + nf * 16 + lr;
                        if (kcol > qrow) sc = -1e30f;
                        sv[nf][r] = sc;
                        mx = fmaxf(mx, sc);
                    }
                    lmax[r] = mx;
                }
            } else {
#pragma unroll
                for (int r = 0; r < 4; ++r) {
                    float mx = -1e30f;
#pragma unroll
                    for (int nf = 0; nf < 4; ++nf) {
                        float sc = saccB[nf][r];
                        sv[nf][r] = sc;
                        mx = fmaxf(mx, sc);
                    }
                    lmax[r] = mx;
                }
            }

            bool grow = false;
#pragma unroll
            for (int r = 0; r < 4; ++r) grow = grow || (lmax[r] > mB[r] + THR2);
            if (__any(grow)) {
#pragma unroll
                for (int r = 0; r < 4; ++r) {
                    float mx = lmax[r];
#pragma unroll
                    for (int off = 1; off < 16; off <<= 1) mx = fmaxf(mx, __shfl_xor(mx, off, 64));
                    float newm = fmaxf(mB[r], mx);
                    float corr = exp2f(mB[r] - newm);
                    sumB[r] *= corr;
#pragma unroll
                    for (int nf = 0; nf < 4; ++nf) oaccB[nf][r] *= corr;
                    mB[r] = newm;
                }
            }

            float p[4][4];
#pragma unroll
            for (int r = 0; r < 4; ++r) {
#pragma unroll
                for (int nf = 0; nf < 4; ++nf) {
                    float pv = exp2f(sv[nf][r] - mB[r]);
                    p[nf][r] = pv;
                    sumB[r] += pv;
                }
            }

#pragma unroll
            for (int r = 0; r < 4; ++r)
#pragma unroll
                for (int nf = 0; nf < 4; ++nf)
                    pT[w][(l >> 4) * 4 + r][nf * 16 + lr] = f2bf(p[nf][r]);

            __builtin_amdgcn_s_setprio(1);
#pragma unroll
            for (int kf = 0; kf < 2; ++kf) {
                bf16x8 pa = *reinterpret_cast<const bf16x8*>(&pT[w][lr][kf * 32 + lk8]);
#pragma unroll
                for (int nf = 0; nf < 4; ++nf) {
                    bf16x8 vb = *reinterpret_cast<const bf16x8*>(&vT[nf * 16 + lr][kf * 32 + lk8]);
                    oaccB[nf] = mfma16(pa, vb, oaccB[nf]);
                }
            }
            __builtin_amdgcn_s_setprio(0);
        }

        // ---- swap staged tile (skip after last) ----
        if (kt < qtB) {
            __syncthreads();   // all waves done reading kT/vT for this tile
#pragma unroll
            for (int it = 0; it < 2; ++it) {
                int rr = it * 32 + row;
                *reinterpret_cast<uint4*>(&kT[rr][c8]) = kreg[it];
                *reinterpret_cast<uint4*>(&vT[rr][c8]) = vreg[it];
            }
            __syncthreads();   // staged tile visible to all waves
        }
    }

    // ---- epilogue: sum-reduce + normalize + store for BOTH tiles ----
#pragma unroll
    for (int r = 0; r < 4; ++r) {
        float s = sumA[r];
#pragma unroll
        for (int off = 1; off < 16; off <<= 1) s += __shfl_xor(s, off, 64);
        float inv = 1.0f / s;
        int srow = qtA * 64 + srow_in + r;
        size_t obase = ((size_t)(b * SEQ + srow)) * HDIM + h * 64;
#pragma unroll
        for (int nf = 0; nf < 4; ++nf)
            qo_ws[obase + nf * 16 + lr] = f2bf(oaccA[nf][r] * inv);
    }
#pragma unroll
    for (int r = 0; r < 4; ++r) {
        float s = sumB[r];
#pragma unroll
        for (int off = 1; off < 16; off <<= 1) s += __shfl_xor(s, off, 64);
        float inv = 1.0f / s;
        int srow = qtB * 64 + srow_in + r;
        size_t obase = ((size_t)(b * SEQ + srow)) * HDIM + h * 64;
#pragma unroll
        for (int nf = 0; nf < 4; ++nf)
            qo_ws[obase + nf * 16 + lr] = f2bf(oaccB[nf][r] * inv);
    }
}

// ---------------- Kernel 3: MFMA output projection, ROW-TILE PAIRED (VERIFIED r37-r41, byte-identical) ----------------
__launch_bounds__(256, 2)
__global__ void oproj_kernel(const unsigned short* __restrict__ o_ws,
                             const float* __restrict__ Wo,
                             float* __restrict__ out) {
    __shared__ __align__(16) unsigned short aT[2][64][40];
    __shared__ __align__(16) unsigned short bT[64][40];

    const int rt0 = blockIdx.x * 2, ct = blockIdx.y;
    const int t = threadIdx.x, w = t >> 6, l = t & 63;
    const int lr = l & 15, lk8 = (l >> 4) * 8;
    const int arow = t >> 2, kg = t & 3;

    f32x4 acc[2][4];
#pragma unroll
    for (int hf = 0; hf < 2; ++hf)
#pragma unroll
        for (int nf = 0; nf < 4; ++nf)
#pragma unroll
            for (int i = 0; i < 4; ++i) acc[hf][nf][i] = 0.0f;

    for (int k0 = 0; k0 < HDIM; k0 += 32) {
        __syncthreads();
        // stage A (bf16 o) for BOTH row tiles
#pragma unroll
        for (int hf = 0; hf < 2; ++hf)
            *reinterpret_cast<uint4*>(&aT[hf][arow][kg * 8]) =
                *reinterpret_cast<const uint4*>(
                    &o_ws[(size_t)((rt0 + hf) * 64 + arow) * HDIM + k0 + kg * 8]);
        // stage B (Wo) ONCE
        {
            const float4* bp = reinterpret_cast<const float4*>(
                Wo + (size_t)(ct * 64 + arow) * HDIM + k0 + kg * 8);
            float4 b0 = bp[0], b1 = bp[1];
            unsigned short* p = &bT[arow][kg * 8];
            p[0] = f2bf(b0.x); p[1] = f2bf(b0.y); p[2] = f2bf(b0.z); p[3] = f2bf(b0.w);
            p[4] = f2bf(b1.x); p[5] = f2bf(b1.y); p[6] = f2bf(b1.z); p[7] = f2bf(b1.w);
        }
        __syncthreads();

#pragma unroll
        for (int hf = 0; hf < 2; ++hf) {
            bf16x8 af = *reinterpret_cast<const bf16x8*>(&aT[hf][w * 16 + lr][lk8]);
#pragma unroll
            for (int nf = 0; nf < 4; ++nf) {
                bf16x8 bfr = *reinterpret_cast<const bf16x8*>(&bT[nf * 16 + lr][lk8]);
                acc[hf][nf] = mfma16(af, bfr, acc[hf][nf]);
            }
        }
    }

#pragma unroll
    for (int hf = 0; hf < 2; ++hf)
#pragma unroll
        for (int nf = 0; nf < 4; ++nf)
#pragma unroll
            for (int r = 0; r < 4; ++r) {
                int row = (rt0 + hf) * 64 + w * 16 + (l >> 4) * 4 + r;
                out[(size_t)row * HDIM + ct * 64 + nf * 16 + lr] = acc[hf][nf][r];
            }
}

// ---------------- launch ----------------
extern "C" void kernel_launch(void* const* d_in, const int* in_sizes, int n_in,
                              void* d_out, int out_size, void* d_ws, size_t ws_size,
                              hipStream_t stream) {
    const float* x  = (const float*)d_in[0];
    const float* Wq = (const float*)d_in[1];
    const float* Wk = (const float*)d_in[2];
    const float* Wv = (const float*)d_in[3];
    const float* Wo = (const float*)d_in[4];
    float* out = (float*)d_out;   // fp32 output (confirmed)

    char* ws = (char*)d_ws;
    float* cos_t = (float*)(ws + 0);                           //   256 KB
    float* sin_t = (float*)(ws + 262144);                      //   256 KB
    unsigned short* qo_ws = (unsigned short*)(ws + 524288);    // 9.44 MB: q then o, [B*S][576]
    unsigned short* k_ws  = (unsigned short*)(ws + 9961472);   // 3.15 MB: [B][3][S][64]
    unsigned short* vT_ws = (unsigned short*)(ws + 13107200);  // 3.15 MB: [B][3][64][S] (transposed)
    // total ws use: 16,252,928 bytes (known-safe)

    hipLaunchKernelGGL(rope_table_kernel, dim3(256), dim3(256), 0, stream, cos_t, sin_t);
    hipLaunchKernelGGL(qkv_kernel, dim3(64, 15), dim3(256), 0, stream,
                       x, Wq, Wk, Wv, cos_t, sin_t, qo_ws, k_ws, vT_ws);
    hipLaunchKernelGGL(attn_mfma, dim3(16, 9, 4), dim3(256), 0, stream,
                       qo_ws, k_ws, vT_ws);
    hipLaunchKernelGGL(oproj_kernel, dim3(64, 9), dim3(256), 0, stream, qo_ws, Wo, out);
}

// Round 43
// 167.917 us; speedup vs baseline: 1.0046x; 1.0046x over previous
//
#include <hip/hip_runtime.h>
#include <stdint.h>
#include <stddef.h>

#define BATCH   4
#define SEQ     2048
#define HDIM    576
#define NHEADS  9
#define NKV     3
#define HD      64
#define GROUPS  3

typedef __bf16 bf16x8 __attribute__((ext_vector_type(8)));
typedef float  f32x4  __attribute__((ext_vector_type(4)));

__device__ __forceinline__ unsigned short f2bf(float f) {
    union { float f; unsigned u; } x; x.f = f;
    unsigned r = (x.u + 0x7FFFu + ((x.u >> 16) & 1u)) >> 16;
    return (unsigned short)r;
}

__device__ __forceinline__ float bf2f(unsigned short us) {
    union { unsigned u; float f; } x; x.u = ((unsigned)us) << 16;
    return x.f;
}

__device__ __forceinline__ f32x4 mfma16(bf16x8 a, bf16x8 b, f32x4 c) {
    return __builtin_amdgcn_mfma_f32_16x16x32_bf16(a, b, c, 0, 0, 0);
}

// ---------------- Kernel 0: RoPE cos/sin tables [SEQ][32] (verified) ----------------
__global__ void rope_table_kernel(float* __restrict__ cos_t, float* __restrict__ sin_t) {
    int idx = blockIdx.x * blockDim.x + threadIdx.x;
    if (idx >= SEQ * 32) return;
    int s = idx >> 5, i = idx & 31;
    float invf = expf(-(float)i * (9.210340371976184f / 32.0f));  // 10000^(-i/32)
    float ang = (float)s * invf;
    cos_t[idx] = cosf(ang);
    sin_t[idx] = sinf(ang);
}

// ---------------- Kernel 1: MFMA QKV projection, register-RoPE, ROW-TILE PAIRED (VERIFIED r36-r41) ----------------
__launch_bounds__(256, 2)
__global__ void qkv_kernel(const float* __restrict__ x,
                           const float* __restrict__ Wq,
                           const float* __restrict__ Wk,
                           const float* __restrict__ Wv,
                           const float* __restrict__ cos_t,
                           const float* __restrict__ sin_t,
                           unsigned short* __restrict__ qo_ws,
                           unsigned short* __restrict__ k_ws,
                           unsigned short* __restrict__ vT_ws) {
    __shared__ __align__(16) unsigned short aT[2][64][40];
    __shared__ __align__(16) unsigned short bT[64][40];

    const int rt0 = blockIdx.x * 2;  // first of two row tiles
    const int ct = blockIdx.y;       // 0..14: 0-8 Q, 9-11 K, 12-14 V
    const int t = threadIdx.x;
    const int w = t >> 6, l = t & 63;
    const int lr = l & 15, lk8 = (l >> 4) * 8;

    const float* W; int wbase;
    if (ct < 9)       { W = Wq; wbase = ct * 64; }
    else if (ct < 12) { W = Wk; wbase = (ct - 9) * 64; }
    else              { W = Wv; wbase = (ct - 12) * 64; }

    const int arow = t >> 2, kg = t & 3;

    f32x4 acc[2][4];
#pragma unroll
    for (int hf = 0; hf < 2; ++hf)
#pragma unroll
        for (int nf = 0; nf < 4; ++nf)
#pragma unroll
            for (int i = 0; i < 4; ++i) acc[hf][nf][i] = 0.0f;

    for (int k0 = 0; k0 < HDIM; k0 += 32) {
        __syncthreads();
        // stage A for BOTH row tiles
#pragma unroll
        for (int hf = 0; hf < 2; ++hf) {
            const float4* ap = reinterpret_cast<const float4*>(
                x + (size_t)((rt0 + hf) * 64 + arow) * HDIM + k0 + kg * 8);
            float4 a0 = ap[0], a1 = ap[1];
            unsigned short* p = &aT[hf][arow][kg * 8];
            p[0] = f2bf(a0.x); p[1] = f2bf(a0.y); p[2] = f2bf(a0.z); p[3] = f2bf(a0.w);
            p[4] = f2bf(a1.x); p[5] = f2bf(a1.y); p[6] = f2bf(a1.z); p[7] = f2bf(a1.w);
        }
        // stage B ONCE (shared by both row tiles)
        {
            const float4* bp = reinterpret_cast<const float4*>(
                W + (size_t)(wbase + arow) * HDIM + k0 + kg * 8);
            float4 b0 = bp[0], b1 = bp[1];
            unsigned short* p = &bT[arow][kg * 8];
            p[0] = f2bf(b0.x); p[1] = f2bf(b0.y); p[2] = f2bf(b0.z); p[3] = f2bf(b0.w);
            p[4] = f2bf(b1.x); p[5] = f2bf(b1.y); p[6] = f2bf(b1.z); p[7] = f2bf(b1.w);
        }
        __syncthreads();

#pragma unroll
        for (int hf = 0; hf < 2; ++hf) {
            bf16x8 af = *reinterpret_cast<const bf16x8*>(&aT[hf][w * 16 + lr][lk8]);
#pragma unroll
            for (int nf = 0; nf < 4; ++nf) {
                bf16x8 bfr = *reinterpret_cast<const bf16x8*>(&bT[nf * 16 + lr][lk8]);
                acc[hf][nf] = mfma16(af, bfr, acc[hf][nf]);
            }
        }
    }

    // ---- epilogue: register RoPE + DIRECT global stores (verified, looped over halves) ----
    const float QSCALE = 0.18033688011112042f;   // 0.125 * log2(e), folded into Q
    const int rowin = w * 16 + (l >> 4) * 4;
#pragma unroll
    for (int hf = 0; hf < 2; ++hf) {
        const int rt = rt0 + hf;
#pragma unroll
        for (int r = 0; r < 4; ++r) {
            const int grow = rt * 64 + rowin + r;
            const int b = grow >> 11, s = grow & 2047;
            if (ct < 12) {
#pragma unroll
                for (int nf = 0; nf < 2; ++nf) {
                    const int d = nf * 16 + lr;                  // 0..31
                    const float c  = cos_t[s * 32 + d];
                    const float sn = sin_t[s * 32 + d];
                    const float lo = acc[hf][nf][r];             // col d
                    const float hi = acc[hf][nf + 2][r];         // col d+32
                    if (ct < 9) {
                        const size_t base = (size_t)grow * HDIM + ct * 64;
                        qo_ws[base + d]      = f2bf((lo * c - hi * sn) * QSCALE);
                        qo_ws[base + d + 32] = f2bf((hi * c + lo * sn) * QSCALE);
                    } else {
                        const size_t base = (((size_t)(b * NKV + (ct - 9))) * SEQ + s) * HD;
                        k_ws[base + d]      = f2bf(lo * c - hi * sn);
                        k_ws[base + d + 32] = f2bf(hi * c + lo * sn);
                    }
                }
            } else {
                // V transposed: vT_ws[(b*NKV+kh)*HD*SEQ + d*SEQ + s]
                const size_t base = ((size_t)(b * NKV + (ct - 12))) * SEQ * HD;
#pragma unroll
                for (int nf = 0; nf < 4; ++nf)
                    vT_ws[base + (size_t)(nf * 16 + lr) * SEQ + s] = f2bf(acc[hf][nf][r]);
            }
        }
    }
}

// ---------------- Kernel 2: MFMA causal flash attention, MERGED-PHASE TRIANGLE PAIR (VERIFIED r41) ----------------
// The two paired q-tiles (qtA=pairi, qtB=31-pairi, qtA<qtB) share ONE K/V sweep kt=0..qtB.
// Tile B computes every iter; tile A only while kt<=qtA (wave-uniform branch). Stage+barrier
// iterations 33 -> 32-pairi (avg 24.5, -26%). pT reused A-then-B within an iter (same-wave
// DS ordering, verified since r19).
__launch_bounds__(256, 2)
__global__ void attn_mfma(unsigned short* __restrict__ qo_ws,
                          const unsigned short* __restrict__ k_ws,
                          const unsigned short* __restrict__ vT_ws) {
    __shared__ __align__(16) unsigned short kT[64][72];
    __shared__ __align__(16) unsigned short vT[64][72];   // [d][kv]
    __shared__ __align__(16) unsigned short pT[4][16][72];

    // ---- XCD-aware work-id swizzle (bijective for 576 blocks, verified r28..r41) ----
    const int flat = blockIdx.x + 16 * (blockIdx.y + 9 * blockIdx.z);  // 0..575 launch id
    const int wsort = (flat % 8) * 72 + (flat / 8);                    // same-XCD => contiguous work
    const int g = wsort / 48;                 // 0..11 = b*3 + kh
    const int rem = wsort % 48;
    const int b = g / 3, kh = g % 3;
    const int hg = rem / 16, pairi = rem % 16;
    const int h = kh * 3 + hg;

    const int t = threadIdx.x, w = t >> 6, l = t & 63;
    const int lr = l & 15, lk8 = (l >> 4) * 8;

    const size_t kvbase = ((size_t)(b * NKV + kh)) * SEQ * HD;  // same extent for k_ws and vT_ws
    const int row = t >> 3, c8 = (t & 7) * 8;
    const int srow_in = w * 16 + (l >> 4) * 4;

    const float THR2 = 11.541560327111708f;    // 8 nats in log2 units

    const int qtA = pairi;          // small tile
    const int qtB = 31 - pairi;     // large tile (qtA < qtB always: pairi <= 15)

    // ---- Q fragments for BOTH tiles (pre-scaled by 0.125*log2e at qkv time) ----
    size_t qbaseA = ((size_t)(b * SEQ + qtA * 64 + w * 16 + lr)) * HDIM + h * 64;
    size_t qbaseB = ((size_t)(b * SEQ + qtB * 64 + w * 16 + lr)) * HDIM + h * 64;
    bf16x8 qaA[2], qaB[2];
    qaA[0] = *reinterpret_cast<const bf16x8*>(&qo_ws[qbaseA + lk8]);
    qaA[1] = *reinterpret_cast<const bf16x8*>(&qo_ws[qbaseA + 32 + lk8]);
    qaB[0] = *reinterpret_cast<const bf16x8*>(&qo_ws[qbaseB + lk8]);
    qaB[1] = *reinterpret_cast<const bf16x8*>(&qo_ws[qbaseB + 32 + lk8]);

    float mA[4], mB[4], sumA[4], sumB[4];
    f32x4 oaccA[4], oaccB[4];
#pragma unroll
    for (int r = 0; r < 4; ++r) { mA[r] = -1e30f; mB[r] = -1e30f; sumA[r] = 0.f; sumB[r] = 0.f; }
#pragma unroll
    for (int nf = 0; nf < 4; ++nf)
#pragma unroll
        for (int i = 0; i < 4; ++i) { oaccA[nf][i] = 0.0f; oaccB[nf][i] = 0.0f; }

    uint4 kreg[2], vreg[2];
    // prologue: load tile 0 into regs, then LDS
#pragma unroll
    for (int it = 0; it < 2; ++it) {
        int rr = it * 32 + row;
        kreg[it] = *reinterpret_cast<const uint4*>(&k_ws[kvbase + (size_t)rr * HD + c8]);
        vreg[it] = *reinterpret_cast<const uint4*>(&vT_ws[kvbase + (size_t)rr * SEQ + c8]);
    }
    __syncthreads();
#pragma unroll
    for (int it = 0; it < 2; ++it) {
        int rr = it * 32 + row;
        *reinterpret_cast<uint4*>(&kT[rr][c8]) = kreg[it];
        *reinterpret_cast<uint4*>(&vT[rr][c8]) = vreg[it];
    }
    __syncthreads();

    for (int kt = 0; kt <= qtB; ++kt) {
        // ---- prefetch next tile into registers (latency hidden under compute) ----
        if (kt < qtB) {
#pragma unroll
            for (int it = 0; it < 2; ++it) {
                int rr = it * 32 + row;
                kreg[it] = *reinterpret_cast<const uint4*>(
                    &k_ws[kvbase + (size_t)((kt + 1) * 64 + rr) * HD + c8]);
                vreg[it] = *reinterpret_cast<const uint4*>(
                    &vT_ws[kvbase + (size_t)rr * SEQ + (kt + 1) * 64 + c8]);
            }
        }

        // ================= TILE A (active while kt <= qtA) =================
        if (kt <= qtA) {
            f32x4 sacc[4];
#pragma unroll
            for (int nf = 0; nf < 4; ++nf)
#pragma unroll
                for (int i = 0; i < 4; ++i) sacc[nf][i] = 0.0f;
            __builtin_amdgcn_s_setprio(1);
#pragma unroll
            for (int kf = 0; kf < 2; ++kf) {
#pragma unroll
                for (int nf = 0; nf < 4; ++nf) {
                    bf16x8 bfr = *reinterpret_cast<const bf16x8*>(&kT[nf * 16 + lr][kf * 32 + lk8]);
                    sacc[nf] = mfma16(qaA[kf], bfr, sacc[nf]);
                }
            }
            __builtin_amdgcn_s_setprio(0);

            float sv[4][4], lmax[4];
            if (kt == qtA) {
#pragma unroll
                for (int r = 0; r < 4; ++r) {
                    int qrow = qtA * 64 + srow_in + r;
                    float mx = -1e30f;
#pragma unroll
                    for (int nf = 0; nf < 4; ++nf) {
                        float sc = sacc[nf][r];
                        int kcol = kt * 64 + nf * 16 + lr;
                        if (kcol > qrow) sc = -1e30f;
                        sv[nf][r] = sc;
                        mx = fmaxf(mx, sc);
                    }
                    lmax[r] = mx;
                }
            } else {
#pragma unroll
                for (int r = 0; r < 4; ++r) {
                    float mx = -1e30f;
#pragma unroll
                    for (int nf = 0; nf < 4; ++nf) {
                        float sc = sacc[nf][r];
                        sv[nf][r] = sc;
                        mx = fmaxf(mx, sc);
                    }
                    lmax[r] = mx;
                }
            }

            bool grow = false;
#pragma unroll
            for (int r = 0; r < 4; ++r) grow = grow || (lmax[r] > mA[r] + THR2);
            if (__any(grow)) {
#pragma unroll
                for (int r = 0; r < 4; ++r) {
                    float mx = lmax[r];
#pragma unroll
                    for (int off = 1; off < 16; off <<= 1) mx = fmaxf(mx, __shfl_xor(mx, off, 64));
                    float newm = fmaxf(mA[r], mx);
                    float corr = exp2f(mA[r] - newm);
                    sumA[r] *= corr;
#pragma unroll
                    for (int nf = 0; nf < 4; ++nf) oaccA[nf][r] *= corr;
                    mA[r] = newm;
                }
            }

            float p[4][4];
#pragma unroll
            for (int r = 0; r < 4; ++r) {
#pragma unroll
                for (int nf = 0; nf < 4; ++nf) {
                    float pv = exp2f(sv[nf][r] - mA[r]);
                    p[nf][r] = pv;
                    sumA[r] += pv;
                }
            }

#pragma unroll
            for (int r = 0; r < 4; ++r)
#pragma unroll
                for (int nf = 0; nf < 4; ++nf)
                    pT[w][(l >> 4) * 4 + r][nf * 16 + lr] = f2bf(p[nf][r]);

            __builtin_amdgcn_s_setprio(1);
#pragma unroll
            for (int kf = 0; kf < 2; ++kf) {
                bf16x8 pa = *reinterpret_cast<const bf16x8*>(&pT[w][lr][kf * 32 + lk8]);
#pragma unroll
                for (int nf = 0; nf < 4; ++nf) {
                    bf16x8 vb = *reinterpret_cast<const bf16x8*>(&vT[nf * 16 + lr][kf * 32 + lk8]);
                    oaccA[nf] = mfma16(pa, vb, oaccA[nf]);
                }
            }
            __builtin_amdgcn_s_setprio(0);
        }

        // ================= TILE B (always active) =================
        {
            f32x4 sacc[4];
#pragma unroll
            for (int nf = 0; nf < 4; ++nf)
#pragma unroll
                for (int i = 0; i < 4; ++i) sacc[nf][i] = 0.0f;
            __builtin_amdgcn_s_setprio(1);
#pragma unroll
            for (int kf = 0; kf < 2; ++kf) {
#pragma unroll
                for (int nf = 0; nf < 4; ++nf) {
                    bf16x8 bfr = *reinterpret_cast<const bf16x8*>(&kT[nf * 16 + lr][kf * 32 + lk8]);
                    sacc[nf] = mfma16(qaB[kf], bfr, sacc[nf]);
                }
            }
            __builtin_amdgcn_s_setprio(0);

            float sv[4][4], lmax[4];
            if (kt == qtB) {
#pragma unroll
                for (int r = 0; r < 4; ++r) {
                    int qrow = qtB * 64 + srow_in + r;
                    float mx = -1e30f;
#pragma unroll
                    for (int nf = 0; nf < 4; ++nf) {
                        float sc = sacc[nf][r];
                        int kcol = kt * 64 + nf * 16 + lr;
                        if (kcol > qrow) sc = -1e30f;
                        sv[nf][r] = sc;
                        mx = fmaxf(mx, sc);
                    }
                    lmax[r] = mx;
                }
            } else {
#pragma unroll
                for (int r = 0; r < 4; ++r) {
                    float mx = -1e30f;
#pragma unroll
                    for (int nf = 0; nf < 4; ++nf) {
                        float sc = sacc[nf][r];
                        sv[nf][r] = sc;
                        mx = fmaxf(mx, sc);
                    }
                    lmax[r] = mx;
                }
            }

            bool grow = false;
#pragma unroll
            for (int r = 0; r < 4; ++r) grow = grow || (lmax[r] > mB[r] + THR2);
            if (__any(grow)) {
#pragma unroll
                for (int r = 0; r < 4; ++r) {
                    float mx = lmax[r];
#pragma unroll
                    for (int off = 1; off < 16; off <<= 1) mx = fmaxf(mx, __shfl_xor(mx, off, 64));
                    float newm = fmaxf(mB[r], mx);
                    float corr = exp2f(mB[r] - newm);
                    sumB[r] *= corr;
#pragma unroll
                    for (int nf = 0; nf < 4; ++nf) oaccB[nf][r] *= corr;
                    mB[r] = newm;
                }
            }

            float p[4][4];
#pragma unroll
            for (int r = 0; r < 4; ++r) {
#pragma unroll
                for (int nf = 0; nf < 4; ++nf) {
                    float pv = exp2f(sv[nf][r] - mB[r]);
                    p[nf][r] = pv;
                    sumB[r] += pv;
                }
            }

#pragma unroll
            for (int r = 0; r < 4; ++r)
#pragma unroll
                for (int nf = 0; nf < 4; ++nf)
                    pT[w][(l >> 4) * 4 + r][nf * 16 + lr] = f2bf(p[nf][r]);

            __builtin_amdgcn_s_setprio(1);
#pragma unroll
            for (int kf = 0; kf < 2; ++kf) {
                bf16x8 pa = *reinterpret_cast<const bf16x8*>(&pT[w][lr][kf * 32 + lk8]);
#pragma unroll
                for (int nf = 0; nf < 4; ++nf) {
                    bf16x8 vb = *reinterpret_cast<const bf16x8*>(&vT[nf * 16 + lr][kf * 32 + lk8]);
                    oaccB[nf] = mfma16(pa, vb, oaccB[nf]);
                }
            }
            __builtin_amdgcn_s_setprio(0);
        }

        // ---- swap staged tile (skip after last) ----
        if (kt < qtB) {
            __syncthreads();   // all waves done reading kT/vT for this tile
#pragma unroll
            for (int it = 0; it < 2; ++it) {
                int rr = it * 32 + row;
                *reinterpret_cast<uint4*>(&kT[rr][c8]) = kreg[it];
                *reinterpret_cast<uint4*>(&vT[rr][c8]) = vreg[it];
            }
            __syncthreads();   // staged tile visible to all waves
        }
    }

    // ---- epilogue: sum-reduce + normalize + store for BOTH tiles ----
#pragma unroll
    for (int r = 0; r < 4; ++r) {
        float s = sumA[r];
#pragma unroll
        for (int off = 1; off < 16; off <<= 1) s += __shfl_xor(s, off, 64);
        float inv = 1.0f / s;
        int srow = qtA * 64 + srow_in + r;
        size_t obase = ((size_t)(b * SEQ + srow)) * HDIM + h * 64;
#pragma unroll
        for (int nf = 0; nf < 4; ++nf)
            qo_ws[obase + nf * 16 + lr] = f2bf(oaccA[nf][r] * inv);
    }
#pragma unroll
    for (int r = 0; r < 4; ++r) {
        float s = sumB[r];
#pragma unroll
        for (int off = 1; off < 16; off <<= 1) s += __shfl_xor(s, off, 64);
        float inv = 1.0f / s;
        int srow = qtB * 64 + srow_in + r;
        size_t obase = ((size_t)(b * SEQ + srow)) * HDIM + h * 64;
#pragma unroll
        for (int nf = 0; nf < 4; ++nf)
            qo_ws[obase + nf * 16 + lr] = f2bf(oaccB[nf][r] * inv);
    }
}

// ---------------- Kernel 3: MFMA output projection, ROW-TILE PAIRED (VERIFIED r37-r41, byte-identical) ----------------
__launch_bounds__(256, 2)
__global__ void oproj_kernel(const unsigned short* __restrict__ o_ws,
                             const float* __restrict__ Wo,
                             float* __restrict__ out) {
    __shared__ __align__(16) unsigned short aT[2][64][40];
    __shared__ __align__(16) unsigned short bT[64][40];

    const int rt0 = blockIdx.x * 2, ct = blockIdx.y;
    const int t = threadIdx.x, w = t >> 6, l = t & 63;
    const int lr = l & 15, lk8 = (l >> 4) * 8;
    const int arow = t >> 2, kg = t & 3;

    f32x4 acc[2][4];
#pragma unroll
    for (int hf = 0; hf < 2; ++hf)
#pragma unroll
        for (int nf = 0; nf < 4; ++nf)
#pragma unroll
            for (int i = 0; i < 4; ++i) acc[hf][nf][i] = 0.0f;

    for (int k0 = 0; k0 < HDIM; k0 += 32) {
        __syncthreads();
        // stage A (bf16 o) for BOTH row tiles
#pragma unroll
        for (int hf = 0; hf < 2; ++hf)
            *reinterpret_cast<uint4*>(&aT[hf][arow][kg * 8]) =
                *reinterpret_cast<const uint4*>(
                    &o_ws[(size_t)((rt0 + hf) * 64 + arow) * HDIM + k0 + kg * 8]);
        // stage B (Wo) ONCE
        {
            const float4* bp = reinterpret_cast<const float4*>(
                Wo + (size_t)(ct * 64 + arow) * HDIM + k0 + kg * 8);
            float4 b0 = bp[0], b1 = bp[1];
            unsigned short* p = &bT[arow][kg * 8];
            p[0] = f2bf(b0.x); p[1] = f2bf(b0.y); p[2] = f2bf(b0.z); p[3] = f2bf(b0.w);
            p[4] = f2bf(b1.x); p[5] = f2bf(b1.y); p[6] = f2bf(b1.z); p[7] = f2bf(b1.w);
        }
        __syncthreads();

#pragma unroll
        for (int hf = 0; hf < 2; ++hf) {
            bf16x8 af = *reinterpret_cast<const bf16x8*>(&aT[hf][w * 16 + lr][lk8]);
#pragma unroll
            for (int nf = 0; nf < 4; ++nf) {
                bf16x8 bfr = *reinterpret_cast<const bf16x8*>(&bT[nf * 16 + lr][lk8]);
                acc[hf][nf] = mfma16(af, bfr, acc[hf][nf]);
            }
        }
    }

#pragma unroll
    for (int hf = 0; hf < 2; ++hf)
#pragma unroll
        for (int nf = 0; nf < 4; ++nf)
#pragma unroll
            for (int r = 0; r < 4; ++r) {
                int row = (rt0 + hf) * 64 + w * 16 + (l >> 4) * 4 + r;
                out[(size_t)row * HDIM + ct * 64 + nf * 16 + lr] = acc[hf][nf][r];
            }
}

// ---------------- launch ----------------
extern "C" void kernel_launch(void* const* d_in, const int* in_sizes, int n_in,
                              void* d_out, int out_size, void* d_ws, size_t ws_size,
                              hipStream_t stream) {
    const float* x  = (const float*)d_in[0];
    const float* Wq = (const float*)d_in[1];
    const float* Wk = (const float*)d_in[2];
    const float* Wv = (const float*)d_in[3];
    const float* Wo = (const float*)d_in[4];
    float* out = (float*)d_out;   // fp32 output (confirmed)

    char* ws = (char*)d_ws;
    float* cos_t = (float*)(ws + 0);                           //   256 KB
    float* sin_t = (float*)(ws + 262144);                      //   256 KB
    unsigned short* qo_ws = (unsigned short*)(ws + 524288);    // 9.44 MB: q then o, [B*S][576]
    unsigned short* k_ws  = (unsigned short*)(ws + 9961472);   // 3.15 MB: [B][3][S][64]
    unsigned short* vT_ws = (unsigned short*)(ws + 13107200);  // 3.15 MB: [B][3][64][S] (transposed)
    // total ws use: 16,252,928 bytes (known-safe)

    hipLaunchKernelGGL(rope_table_kernel, dim3(256), dim3(256), 0, stream, cos_t, sin_t);
    hipLaunchKernelGGL(qkv_kernel, dim3(64, 15), dim3(256), 0, stream,
                       x, Wq, Wk, Wv, cos_t, sin_t, qo_ws, k_ws, vT_ws);
    hipLaunchKernelGGL(attn_mfma, dim3(16, 9, 4), dim3(256), 0, stream,
                       qo_ws, k_ws, vT_ws);
    hipLaunchKernelGGL(oproj_kernel, dim3(64, 9), dim3(256), 0, stream, qo_ws, Wo, out);
}

// Round 44
// 167.703 us; speedup vs baseline: 1.0059x; 1.0013x over previous
//
#include <hip/hip_runtime.h>
#include <stdint.h>
#include <stddef.h>

#define BATCH   4
#define SEQ     2048
#define HDIM    576
#define NHEADS  9
#define NKV     3
#define HD      64
#define GROUPS  3

typedef __bf16 bf16x8 __attribute__((ext_vector_type(8)));
typedef float  f32x4  __attribute__((ext_vector_type(4)));

__device__ __forceinline__ unsigned short f2bf(float f) {
    union { float f; unsigned u; } x; x.f = f;
    unsigned r = (x.u + 0x7FFFu + ((x.u >> 16) & 1u)) >> 16;
    return (unsigned short)r;
}

__device__ __forceinline__ float bf2f(unsigned short us) {
    union { unsigned u; float f; } x; x.u = ((unsigned)us) << 16;
    return x.f;
}

__device__ __forceinline__ f32x4 mfma16(bf16x8 a, bf16x8 b, f32x4 c) {
    return __builtin_amdgcn_mfma_f32_16x16x32_bf16(a, b, c, 0, 0, 0);
}

// ---------------- Kernel 0: RoPE cos/sin tables [SEQ][32] (verified) ----------------
__global__ void rope_table_kernel(float* __restrict__ cos_t, float* __restrict__ sin_t) {
    int idx = blockIdx.x * blockDim.x + threadIdx.x;
    if (idx >= SEQ * 32) return;
    int s = idx >> 5, i = idx & 31;
    float invf = expf(-(float)i * (9.210340371976184f / 32.0f));  // 10000^(-i/32)
    float ang = (float)s * invf;
    cos_t[idx] = cosf(ang);
    sin_t[idx] = sinf(ang);
}

// ---------------- Kernel 1: MFMA QKV projection, register-RoPE, ROW-TILE PAIRED (VERIFIED r36-r43) ----------------
__launch_bounds__(256, 2)
__global__ void qkv_kernel(const float* __restrict__ x,
                           const float* __restrict__ Wq,
                           const float* __restrict__ Wk,
                           const float* __restrict__ Wv,
                           const float* __restrict__ cos_t,
                           const float* __restrict__ sin_t,
                           unsigned short* __restrict__ qo_ws,
                           unsigned short* __restrict__ k_ws,
                           unsigned short* __restrict__ vT_ws) {
    __shared__ __align__(16) unsigned short aT[2][64][40];
    __shared__ __align__(16) unsigned short bT[64][40];

    const int rt0 = blockIdx.x * 2;  // first of two row tiles
    const int ct = blockIdx.y;       // 0..14: 0-8 Q, 9-11 K, 12-14 V
    const int t = threadIdx.x;
    const int w = t >> 6, l = t & 63;
    const int lr = l & 15, lk8 = (l >> 4) * 8;

    const float* W; int wbase;
    if (ct < 9)       { W = Wq; wbase = ct * 64; }
    else if (ct < 12) { W = Wk; wbase = (ct - 9) * 64; }
    else              { W = Wv; wbase = (ct - 12) * 64; }

    const int arow = t >> 2, kg = t & 3;

    f32x4 acc[2][4];
#pragma unroll
    for (int hf = 0; hf < 2; ++hf)
#pragma unroll
        for (int nf = 0; nf < 4; ++nf)
#pragma unroll
            for (int i = 0; i < 4; ++i) acc[hf][nf][i] = 0.0f;

    for (int k0 = 0; k0 < HDIM; k0 += 32) {
        __syncthreads();
        // stage A for BOTH row tiles
#pragma unroll
        for (int hf = 0; hf < 2; ++hf) {
            const float4* ap = reinterpret_cast<const float4*>(
                x + (size_t)((rt0 + hf) * 64 + arow) * HDIM + k0 + kg * 8);
            float4 a0 = ap[0], a1 = ap[1];
            unsigned short* p = &aT[hf][arow][kg * 8];
            p[0] = f2bf(a0.x); p[1] = f2bf(a0.y); p[2] = f2bf(a0.z); p[3] = f2bf(a0.w);
            p[4] = f2bf(a1.x); p[5] = f2bf(a1.y); p[6] = f2bf(a1.z); p[7] = f2bf(a1.w);
        }
        // stage B ONCE (shared by both row tiles)
        {
            const float4* bp = reinterpret_cast<const float4*>(
                W + (size_t)(wbase + arow) * HDIM + k0 + kg * 8);
            float4 b0 = bp[0], b1 = bp[1];
            unsigned short* p = &bT[arow][kg * 8];
            p[0] = f2bf(b0.x); p[1] = f2bf(b0.y); p[2] = f2bf(b0.z); p[3] = f2bf(b0.w);
            p[4] = f2bf(b1.x); p[5] = f2bf(b1.y); p[6] = f2bf(b1.z); p[7] = f2bf(b1.w);
        }
        __syncthreads();

#pragma unroll
        for (int hf = 0; hf < 2; ++hf) {
            bf16x8 af = *reinterpret_cast<const bf16x8*>(&aT[hf][w * 16 + lr][lk8]);
#pragma unroll
            for (int nf = 0; nf < 4; ++nf) {
                bf16x8 bfr = *reinterpret_cast<const bf16x8*>(&bT[nf * 16 + lr][lk8]);
                acc[hf][nf] = mfma16(af, bfr, acc[hf][nf]);
            }
        }
    }

    // ---- epilogue: register RoPE + DIRECT global stores (verified, looped over halves) ----
    const float QSCALE = 0.18033688011112042f;   // 0.125 * log2(e), folded into Q
    const int rowin = w * 16 + (l >> 4) * 4;
#pragma unroll
    for (int hf = 0; hf < 2; ++hf) {
        const int rt = rt0 + hf;
#pragma unroll
        for (int r = 0; r < 4; ++r) {
            const int grow = rt * 64 + rowin + r;
            const int b = grow >> 11, s = grow & 2047;
            if (ct < 12) {
#pragma unroll
                for (int nf = 0; nf < 2; ++nf) {
                    const int d = nf * 16 + lr;                  // 0..31
                    const float c  = cos_t[s * 32 + d];
                    const float sn = sin_t[s * 32 + d];
                    const float lo = acc[hf][nf][r];             // col d
                    const float hi = acc[hf][nf + 2][r];         // col d+32
                    if (ct < 9) {
                        const size_t base = (size_t)grow * HDIM + ct * 64;
                        qo_ws[base + d]      = f2bf((lo * c - hi * sn) * QSCALE);
                        qo_ws[base + d + 32] = f2bf((hi * c + lo * sn) * QSCALE);
                    } else {
                        const size_t base = (((size_t)(b * NKV + (ct - 9))) * SEQ + s) * HD;
                        k_ws[base + d]      = f2bf(lo * c - hi * sn);
                        k_ws[base + d + 32] = f2bf(hi * c + lo * sn);
                    }
                }
            } else {
                // V transposed: vT_ws[(b*NKV+kh)*HD*SEQ + d*SEQ + s]
                const size_t base = ((size_t)(b * NKV + (ct - 12))) * SEQ * HD;
#pragma unroll
                for (int nf = 0; nf < 4; ++nf)
                    vT_ws[base + (size_t)(nf * 16 + lr) * SEQ + s] = f2bf(acc[hf][nf][r]);
            }
        }
    }
}

// ---------------- Kernel 2: MFMA causal flash attention, MERGED-PHASE TRIANGLE PAIR (VERIFIED r41/r43) ----------------
// The two paired q-tiles (qtA=pairi, qtB=31-pairi, qtA<qtB) share ONE K/V sweep kt=0..qtB.
// Tile B computes every iter; tile A only while kt<=qtA (wave-uniform branch). Stage+barrier
// iterations 33 -> 32-pairi (avg 24.5, -26%). pT reused A-then-B within an iter (same-wave
// DS ordering, verified since r19).
__launch_bounds__(256, 2)
__global__ void attn_mfma(unsigned short* __restrict__ qo_ws,
                          const unsigned short* __restrict__ k_ws,
                          const unsigned short* __restrict__ vT_ws) {
    __shared__ __align__(16) unsigned short kT[64][72];
    __shared__ __align__(16) unsigned short vT[64][72];   // [d][kv]
    __shared__ __align__(16) unsigned short pT[4][16][72];

    // ---- XCD-aware work-id swizzle (bijective for 576 blocks, verified r28..r43) ----
    const int flat = blockIdx.x + 16 * (blockIdx.y + 9 * blockIdx.z);  // 0..575 launch id
    const int wsort = (flat % 8) * 72 + (flat / 8);                    // same-XCD => contiguous work
    const int g = wsort / 48;                 // 0..11 = b*3 + kh
    const int rem = wsort % 48;
    const int b = g / 3, kh = g % 3;
    const int hg = rem / 16, pairi = rem % 16;
    const int h = kh * 3 + hg;

    const int t = threadIdx.x, w = t >> 6, l = t & 63;
    const int lr = l & 15, lk8 = (l >> 4) * 8;

    const size_t kvbase = ((size_t)(b * NKV + kh)) * SEQ * HD;  // same extent for k_ws and vT_ws
    const int row = t >> 3, c8 = (t & 7) * 8;
    const int srow_in = w * 16 + (l >> 4) * 4;

    const float THR2 = 11.541560327111708f;    // 8 nats in log2 units

    const int qtA = pairi;          // small tile
    const int qtB = 31 - pairi;     // large tile (qtA < qtB always: pairi <= 15)

    // ---- Q fragments for BOTH tiles (pre-scaled by 0.125*log2e at qkv time) ----
    size_t qbaseA = ((size_t)(b * SEQ + qtA * 64 + w * 16 + lr)) * HDIM + h * 64;
    size_t qbaseB = ((size_t)(b * SEQ + qtB * 64 + w * 16 + lr)) * HDIM + h * 64;
    bf16x8 qaA[2], qaB[2];
    qaA[0] = *reinterpret_cast<const bf16x8*>(&qo_ws[qbaseA + lk8]);
    qaA[1] = *reinterpret_cast<const bf16x8*>(&qo_ws[qbaseA + 32 + lk8]);
    qaB[0] = *reinterpret_cast<const bf16x8*>(&qo_ws[qbaseB + lk8]);
    qaB[1] = *reinterpret_cast<const bf16x8*>(&qo_ws[qbaseB + 32 + lk8]);

    float mA[4], mB[4], sumA[4], sumB[4];
    f32x4 oaccA[4], oaccB[4];
#pragma unroll
    for (int r = 0; r < 4; ++r) { mA[r] = -1e30f; mB[r] = -1e30f; sumA[r] = 0.f; sumB[r] = 0.f; }
#pragma unroll
    for (int nf = 0; nf < 4; ++nf)
#pragma unroll
        for (int i = 0; i < 4; ++i) { oaccA[nf][i] = 0.0f; oaccB[nf][i] = 0.0f; }

    uint4 kreg[2], vreg[2];
    // prologue: load tile 0 into regs, then LDS
#pragma unroll
    for (int it = 0; it < 2; ++it) {
        int rr = it * 32 + row;
        kreg[it] = *reinterpret_cast<const uint4*>(&k_ws[kvbase + (size_t)rr * HD + c8]);
        vreg[it] = *reinterpret_cast<const uint4*>(&vT_ws[kvbase + (size_t)rr * SEQ + c8]);
    }
    __syncthreads();
#pragma unroll
    for (int it = 0; it < 2; ++it) {
        int rr = it * 32 + row;
        *reinterpret_cast<uint4*>(&kT[rr][c8]) = kreg[it];
        *reinterpret_cast<uint4*>(&vT[rr][c8]) = vreg[it];
    }
    __syncthreads();

    for (int kt = 0; kt <= qtB; ++kt) {
        // ---- prefetch next tile into registers (latency hidden under compute) ----
        if (kt < qtB) {
#pragma unroll
            for (int it = 0; it < 2; ++it) {
                int rr = it * 32 + row;
                kreg[it] = *reinterpret_cast<const uint4*>(
                    &k_ws[kvbase + (size_t)((kt + 1) * 64 + rr) * HD + c8]);
                vreg[it] = *reinterpret_cast<const uint4*>(
                    &vT_ws[kvbase + (size_t)rr * SEQ + (kt + 1) * 64 + c8]);
            }
        }

        // ================= TILE A (active while kt <= qtA) =================
        if (kt <= qtA) {
            f32x4 sacc[4];
#pragma unroll
            for (int nf = 0; nf < 4; ++nf)
#pragma unroll
                for (int i = 0; i < 4; ++i) sacc[nf][i] = 0.0f;
            __builtin_amdgcn_s_setprio(1);
#pragma unroll
            for (int kf = 0; kf < 2; ++kf) {
#pragma unroll
                for (int nf = 0; nf < 4; ++nf) {
                    bf16x8 bfr = *reinterpret_cast<const bf16x8*>(&kT[nf * 16 + lr][kf * 32 + lk8]);
                    sacc[nf] = mfma16(qaA[kf], bfr, sacc[nf]);
                }
            }
            __builtin_amdgcn_s_setprio(0);

            float sv[4][4], lmax[4];
            if (kt == qtA) {
#pragma unroll
                for (int r = 0; r < 4; ++r) {
                    int qrow = qtA * 64 + srow_in + r;
                    float mx = -1e30f;
#pragma unroll
                    for (int nf = 0; nf < 4; ++nf) {
                        float sc = sacc[nf][r];
                        int kcol = kt * 64 + nf * 16 + lr;
                        if (kcol > qrow) sc = -1e30f;
                        sv[nf][r] = sc;
                        mx = fmaxf(mx, sc);
                    }
                    lmax[r] = mx;
                }
            } else {
#pragma unroll
                for (int r = 0; r < 4; ++r) {
                    float mx = -1e30f;
#pragma unroll
                    for (int nf = 0; nf < 4; ++nf) {
                        float sc = sacc[nf][r];
                        sv[nf][r] = sc;
                        mx = fmaxf(mx, sc);
                    }
                    lmax[r] = mx;
                }
            }

            bool grow = false;
#pragma unroll
            for (int r = 0; r < 4; ++r) grow = grow || (lmax[r] > mA[r] + THR2);
            if (__any(grow)) {
#pragma unroll
                for (int r = 0; r < 4; ++r) {
                    float mx = lmax[r];
#pragma unroll
                    for (int off = 1; off < 16; off <<= 1) mx = fmaxf(mx, __shfl_xor(mx, off, 64));
                    float newm = fmaxf(mA[r], mx);
                    float corr = exp2f(mA[r] - newm);
                    sumA[r] *= corr;
#pragma unroll
                    for (int nf = 0; nf < 4; ++nf) oaccA[nf][r] *= corr;
                    mA[r] = newm;
                }
            }

            float p[4][4];
#pragma unroll
            for (int r = 0; r < 4; ++r) {
#pragma unroll
                for (int nf = 0; nf < 4; ++nf) {
                    float pv = exp2f(sv[nf][r] - mA[r]);
                    p[nf][r] = pv;
                    sumA[r] += pv;
                }
            }

#pragma unroll
            for (int r = 0; r < 4; ++r)
#pragma unroll
                for (int nf = 0; nf < 4; ++nf)
                    pT[w][(l >> 4) * 4 + r][nf * 16 + lr] = f2bf(p[nf][r]);

            __builtin_amdgcn_s_setprio(1);
#pragma unroll
            for (int kf = 0; kf < 2; ++kf) {
                bf16x8 pa = *reinterpret_cast<const bf16x8*>(&pT[w][lr][kf * 32 + lk8]);
#pragma unroll
                for (int nf = 0; nf < 4; ++nf) {
                    bf16x8 vb = *reinterpret_cast<const bf16x8*>(&vT[nf * 16 + lr][kf * 32 + lk8]);
                    oaccA[nf] = mfma16(pa, vb, oaccA[nf]);
                }
            }
            __builtin_amdgcn_s_setprio(0);
        }

        // ================= TILE B (always active) =================
        {
            f32x4 sacc[4];
#pragma unroll
            for (int nf = 0; nf < 4; ++nf)
#pragma unroll
                for (int i = 0; i < 4; ++i) sacc[nf][i] = 0.0f;
            __builtin_amdgcn_s_setprio(1);
#pragma unroll
            for (int kf = 0; kf < 2; ++kf) {
#pragma unroll
                for (int nf = 0; nf < 4; ++nf) {
                    bf16x8 bfr = *reinterpret_cast<const bf16x8*>(&kT[nf * 16 + lr][kf * 32 + lk8]);
                    sacc[nf] = mfma16(qaB[kf], bfr, sacc[nf]);
                }
            }
            __builtin_amdgcn_s_setprio(0);

            float sv[4][4], lmax[4];
            if (kt == qtB) {
#pragma unroll
                for (int r = 0; r < 4; ++r) {
                    int qrow = qtB * 64 + srow_in + r;
                    float mx = -1e30f;
#pragma unroll
                    for (int nf = 0; nf < 4; ++nf) {
                        float sc = sacc[nf][r];
                        int kcol = kt * 64 + nf * 16 + lr;
                        if (kcol > qrow) sc = -1e30f;
                        sv[nf][r] = sc;
                        mx = fmaxf(mx, sc);
                    }
                    lmax[r] = mx;
                }
            } else {
#pragma unroll
                for (int r = 0; r < 4; ++r) {
                    float mx = -1e30f;
#pragma unroll
                    for (int nf = 0; nf < 4; ++nf) {
                        float sc = sacc[nf][r];
                        sv[nf][r] = sc;
                        mx = fmaxf(mx, sc);
                    }
                    lmax[r] = mx;
                }
            }

            bool grow = false;
#pragma unroll
            for (int r = 0; r < 4; ++r) grow = grow || (lmax[r] > mB[r] + THR2);
            if (__any(grow)) {
#pragma unroll
                for (int r = 0; r < 4; ++r) {
                    float mx = lmax[r];
#pragma unroll
                    for (int off = 1; off < 16; off <<= 1) mx = fmaxf(mx, __shfl_xor(mx, off, 64));
                    float newm = fmaxf(mB[r], mx);
                    float corr = exp2f(mB[r] - newm);
                    sumB[r] *= corr;
#pragma unroll
                    for (int nf = 0; nf < 4; ++nf) oaccB[nf][r] *= corr;
                    mB[r] = newm;
                }
            }

            float p[4][4];
#pragma unroll
            for (int r = 0; r < 4; ++r) {
#pragma unroll
                for (int nf = 0; nf < 4; ++nf) {
                    float pv = exp2f(sv[nf][r] - mB[r]);
                    p[nf][r] = pv;
                    sumB[r] += pv;
                }
            }

#pragma unroll
            for (int r = 0; r < 4; ++r)
#pragma unroll
                for (int nf = 0; nf < 4; ++nf)
                    pT[w][(l >> 4) * 4 + r][nf * 16 + lr] = f2bf(p[nf][r]);

            __builtin_amdgcn_s_setprio(1);
#pragma unroll
            for (int kf = 0; kf < 2; ++kf) {
                bf16x8 pa = *reinterpret_cast<const bf16x8*>(&pT[w][lr][kf * 32 + lk8]);
#pragma unroll
                for (int nf = 0; nf < 4; ++nf) {
                    bf16x8 vb = *reinterpret_cast<const bf16x8*>(&vT[nf * 16 + lr][kf * 32 + lk8]);
                    oaccB[nf] = mfma16(pa, vb, oaccB[nf]);
                }
            }
            __builtin_amdgcn_s_setprio(0);
        }

        // ---- swap staged tile (skip after last) ----
        if (kt < qtB) {
            __syncthreads();   // all waves done reading kT/vT for this tile
#pragma unroll
            for (int it = 0; it < 2; ++it) {
                int rr = it * 32 + row;
                *reinterpret_cast<uint4*>(&kT[rr][c8]) = kreg[it];
                *reinterpret_cast<uint4*>(&vT[rr][c8]) = vreg[it];
            }
            __syncthreads();   // staged tile visible to all waves
        }
    }

    // ---- epilogue: sum-reduce + normalize + store for BOTH tiles ----
#pragma unroll
    for (int r = 0; r < 4; ++r) {
        float s = sumA[r];
#pragma unroll
        for (int off = 1; off < 16; off <<= 1) s += __shfl_xor(s, off, 64);
        float inv = 1.0f / s;
        int srow = qtA * 64 + srow_in + r;
        size_t obase = ((size_t)(b * SEQ + srow)) * HDIM + h * 64;
#pragma unroll
        for (int nf = 0; nf < 4; ++nf)
            qo_ws[obase + nf * 16 + lr] = f2bf(oaccA[nf][r] * inv);
    }
#pragma unroll
    for (int r = 0; r < 4; ++r) {
        float s = sumB[r];
#pragma unroll
        for (int off = 1; off < 16; off <<= 1) s += __shfl_xor(s, off, 64);
        float inv = 1.0f / s;
        int srow = qtB * 64 + srow_in + r;
        size_t obase = ((size_t)(b * SEQ + srow)) * HDIM + h * 64;
#pragma unroll
        for (int nf = 0; nf < 4; ++nf)
            qo_ws[obase + nf * 16 + lr] = f2bf(oaccB[nf][r] * inv);
    }
}

// ---------------- Kernel 3: MFMA output projection, ROW-TILE PAIRED (VERIFIED r37-r43, byte-identical) ----------------
__launch_bounds__(256, 2)
__global__ void oproj_kernel(const unsigned short* __restrict__ o_ws,
                             const float* __restrict__ Wo,
                             float* __restrict__ out) {
    __shared__ __align__(16) unsigned short aT[2][64][40];
    __shared__ __align__(16) unsigned short bT[64][40];

    const int rt0 = blockIdx.x * 2, ct = blockIdx.y;
    const int t = threadIdx.x, w = t >> 6, l = t & 63;
    const int lr = l & 15, lk8 = (l >> 4) * 8;
    const int arow = t >> 2, kg = t & 3;

    f32x4 acc[2][4];
#pragma unroll
    for (int hf = 0; hf < 2; ++hf)
#pragma unroll
        for (int nf = 0; nf < 4; ++nf)
#pragma unroll
            for (int i = 0; i < 4; ++i) acc[hf][nf][i] = 0.0f;

    for (int k0 = 0; k0 < HDIM; k0 += 32) {
        __syncthreads();
        // stage A (bf16 o) for BOTH row tiles
#pragma unroll
        for (int hf = 0; hf < 2; ++hf)
            *reinterpret_cast<uint4*>(&aT[hf][arow][kg * 8]) =
                *reinterpret_cast<const uint4*>(
                    &o_ws[(size_t)((rt0 + hf) * 64 + arow) * HDIM + k0 + kg * 8]);
        // stage B (Wo) ONCE
        {
            const float4* bp = reinterpret_cast<const float4*>(
                Wo + (size_t)(ct * 64 + arow) * HDIM + k0 + kg * 8);
            float4 b0 = bp[0], b1 = bp[1];
            unsigned short* p = &bT[arow][kg * 8];
            p[0] = f2bf(b0.x); p[1] = f2bf(b0.y); p[2] = f2bf(b0.z); p[3] = f2bf(b0.w);
            p[4] = f2bf(b1.x); p[5] = f2bf(b1.y); p[6] = f2bf(b1.z); p[7] = f2bf(b1.w);
        }
        __syncthreads();

#pragma unroll
        for (int hf = 0; hf < 2; ++hf) {
            bf16x8 af = *reinterpret_cast<const bf16x8*>(&aT[hf][w * 16 + lr][lk8]);
#pragma unroll
            for (int nf = 0; nf < 4; ++nf) {
                bf16x8 bfr = *reinterpret_cast<const bf16x8*>(&bT[nf * 16 + lr][lk8]);
                acc[hf][nf] = mfma16(af, bfr, acc[hf][nf]);
            }
        }
    }

#pragma unroll
    for (int hf = 0; hf < 2; ++hf)
#pragma unroll
        for (int nf = 0; nf < 4; ++nf)
#pragma unroll
            for (int r = 0; r < 4; ++r) {
                int row = (rt0 + hf) * 64 + w * 16 + (l >> 4) * 4 + r;
                out[(size_t)row * HDIM + ct * 64 + nf * 16 + lr] = acc[hf][nf][r];
            }
}

// ---------------- launch ----------------
extern "C" void kernel_launch(void* const* d_in, const int* in_sizes, int n_in,
                              void* d_out, int out_size, void* d_ws, size_t ws_size,
                              hipStream_t stream) {
    const float* x  = (const float*)d_in[0];
    const float* Wq = (const float*)d_in[1];
    const float* Wk = (const float*)d_in[2];
    const float* Wv = (const float*)d_in[3];
    const float* Wo = (const float*)d_in[4];
    float* out = (float*)d_out;   // fp32 output (confirmed)

    char* ws = (char*)d_ws;
    float* cos_t = (float*)(ws + 0);                           //   256 KB
    float* sin_t = (float*)(ws + 262144);                      //   256 KB
    unsigned short* qo_ws = (unsigned short*)(ws + 524288);    // 9.44 MB: q then o, [B*S][576]
    unsigned short* k_ws  = (unsigned short*)(ws + 9961472);   // 3.15 MB: [B][3][S][64]
    unsigned short* vT_ws = (unsigned short*)(ws + 13107200);  // 3.15 MB: [B][3][64][S] (transposed)
    // total ws use: 16,252,928 bytes (known-safe)

    hipLaunchKernelGGL(rope_table_kernel, dim3(256), dim3(256), 0, stream, cos_t, sin_t);
    hipLaunchKernelGGL(qkv_kernel, dim3(64, 15), dim3(256), 0, stream,
                       x, Wq, Wk, Wv, cos_t, sin_t, qo_ws, k_ws, vT_ws);
    hipLaunchKernelGGL(attn_mfma, dim3(16, 9, 4), dim3(256), 0, stream,
                       qo_ws, k_ws, vT_ws);
    hipLaunchKernelGGL(oproj_kernel, dim3(64, 9), dim3(256), 0, stream, qo_ws, Wo, out);
}